// Round 4
// baseline (592.361 us; speedup 1.0000x reference)
//
#include <hip/hip_runtime.h>
#include <stdint.h>

typedef unsigned short ushort_t;
typedef __attribute__((ext_vector_type(8))) short bf16x8;
typedef __attribute__((ext_vector_type(4))) float f32x4;
typedef __attribute__((ext_vector_type(4))) unsigned short u16x4;

#define B_ 2
#define T_ 2048
#define D_ 2048
#define H_ 16
#define HD_ 128
#define BT_ 4096

__device__ __forceinline__ ushort_t f2bf(float f) {
  unsigned u = __float_as_uint(f);
  u += 0x7FFFu + ((u >> 16) & 1u);   // RNE
  return (ushort_t)(u >> 16);
}

__device__ __forceinline__ void async16(const void* g, void* l) {
  __builtin_amdgcn_global_load_lds(
      (const __attribute__((address_space(1))) unsigned int*)g,
      (__attribute__((address_space(3))) unsigned int*)l, 16, 0, 0);
}

// ---------------- elementwise cast x -> bf16 ----------------
__global__ void k_cast_x(const float* __restrict__ in, ushort_t* __restrict__ out) {
  int i = blockIdx.x * 256 + threadIdx.x;          // 4 elements per thread
  float4 v = ((const float4*)in)[i];
  u16x4 r = { f2bf(v.x), f2bf(v.y), f2bf(v.z), f2bf(v.w) };
  ((u16x4*)out)[i] = r;
}

// ---------------- weight transpose+cast: w[K][N] f32 -> wt[N][K] bf16 ----------------
__global__ void k_twT(const float* __restrict__ w, ushort_t* __restrict__ wt) {
  __shared__ float tile[32][33];
  int tx = threadIdx.x, ty = threadIdx.y;
  int x = blockIdx.x * 32 + tx;        // N index
  int y0 = blockIdx.y * 32;            // K index
#pragma unroll
  for (int k = 0; k < 4; ++k)
    tile[ty + k * 8][tx] = w[(size_t)(y0 + ty + k * 8) * D_ + x];
  __syncthreads();
  int ox = blockIdx.y * 32 + tx;       // K contiguous on write
  int oy0 = blockIdx.x * 32;           // N
#pragma unroll
  for (int k = 0; k < 4; ++k)
    wt[(size_t)(oy0 + ty + k * 8) * D_ + ox] = f2bf(tile[tx][ty + k * 8]);
}

// ---------------- GEMM: C[M=4096][N=2048] = A(bf16 MxK) * Bt(bf16 NxK)^T + bias ----------------
// EPI 0: store fp32.  1: store bf16.  2: store fp32 + bf16.  3: gate (out = aux * sigmoid(val))
template <int EPI>
__global__ __launch_bounds__(256) void k_gemm(
    const ushort_t* __restrict__ A, const ushort_t* __restrict__ Bt,
    const float* __restrict__ bias, float* __restrict__ outF,
    ushort_t* __restrict__ outB, const float* __restrict__ aux) {
  __shared__ __align__(16) short As[128 * 32];
  __shared__ __align__(16) short Bs[128 * 32];
  const int tid = threadIdx.x;
  const int wid = tid >> 6, lane = tid & 63;
  const int l15 = lane & 15, kq = lane >> 4;
  const int m0 = (wid >> 1) * 64, n0 = (wid & 1) * 64;
  const int tileM = blockIdx.y * 128, tileN = blockIdx.x * 128;

  f32x4 acc[4][4];
#pragma unroll
  for (int i = 0; i < 4; ++i)
#pragma unroll
    for (int j = 0; j < 4; ++j) acc[i][j] = (f32x4){0.f, 0.f, 0.f, 0.f};

  for (int k0 = 0; k0 < D_; k0 += 32) {
#pragma unroll
    for (int rr = 0; rr < 2; ++rr) {
      int chunk = rr * 256 + tid;
      int row = chunk >> 2, p = chunk & 3;
      int gc = p ^ ((row >> 1) & 3);   // XOR-swizzled global chunk (bank-conflict fix)
      async16(A + (size_t)(tileM + row) * D_ + k0 + gc * 8,
              &As[(rr * 256 + wid * 64) * 8]);
      async16(Bt + (size_t)(tileN + row) * D_ + k0 + gc * 8,
              &Bs[(rr * 256 + wid * 64) * 8]);
    }
    __syncthreads();
    bf16x8 a[4], b[4];
#pragma unroll
    for (int i = 0; i < 4; ++i) {
      int row = m0 + i * 16 + l15;
      a[i] = *(const bf16x8*)&As[row * 32 + (kq ^ ((row >> 1) & 3)) * 8];
    }
#pragma unroll
    for (int j = 0; j < 4; ++j) {
      int row = n0 + j * 16 + l15;
      b[j] = *(const bf16x8*)&Bs[row * 32 + (kq ^ ((row >> 1) & 3)) * 8];
    }
#pragma unroll
    for (int i = 0; i < 4; ++i)
#pragma unroll
      for (int j = 0; j < 4; ++j)
        acc[i][j] = __builtin_amdgcn_mfma_f32_16x16x32_bf16(a[i], b[j], acc[i][j], 0, 0, 0);
    __syncthreads();
  }

#pragma unroll
  for (int i = 0; i < 4; ++i) {
#pragma unroll
    for (int j = 0; j < 4; ++j) {
#pragma unroll
      for (int r = 0; r < 4; ++r) {
        int gm = tileM + m0 + i * 16 + kq * 4 + r;   // C/D: row = quad*4 + reg
        int gn = tileN + n0 + j * 16 + l15;          //      col = lane&15
        size_t idx = (size_t)gm * D_ + gn;
        float val = acc[i][j][r] + bias[gn];
        if (EPI == 0) {
          outF[idx] = val;
        } else if (EPI == 1) {
          outB[idx] = f2bf(val);
        } else if (EPI == 2) {
          outF[idx] = val; outB[idx] = f2bf(val);
        } else {
          float sg = 1.f / (1.f + __expf(-val));
          outF[idx] = aux[idx] * sg;
        }
      }
    }
  }
}

// ---------------- fused RMSNorm (full D) + RoPE, fp32 in -> bf16 out (x oscale) ----------------
__global__ void k_normrope(const float* __restrict__ in, const float* __restrict__ g,
                           const float* __restrict__ cs, const float* __restrict__ sn,
                           ushort_t* __restrict__ out, float oscale) {
  const int row = blockIdx.x;            // 0..4095 = b*T + t
  const int t = row & (T_ - 1);
  const float* x = in + (size_t)row * D_;
  const int tid = threadIdx.x;
  float ss = 0.f;
#pragma unroll
  for (int i = tid; i < 512; i += 256) {
    float4 v = ((const float4*)x)[i];
    ss += v.x * v.x + v.y * v.y + v.z * v.z + v.w * v.w;
  }
#pragma unroll
  for (int off = 1; off < 64; off <<= 1) ss += __shfl_xor(ss, off, 64);
  __shared__ float part[4];
  if ((tid & 63) == 0) part[tid >> 6] = ss;
  __syncthreads();
  float rstd = rsqrtf((part[0] + part[1] + part[2] + part[3]) * (1.f / (float)D_) + 1e-6f);
  rstd *= oscale;                        // fold attention scale*log2e into Q
#pragma unroll
  for (int p = tid; p < 1024; p += 256) {
    int head = p >> 6, i = p & 63;
    int e1 = head * HD_ + i, e2 = e1 + 64;
    float x1 = x[e1] * rstd * g[e1];
    float x2 = x[e2] * rstd * g[e2];
    float c = cs[t * 64 + i], s = sn[t * 64 + i];
    out[(size_t)row * D_ + e1] = f2bf(x1 * c - s * x2);
    out[(size_t)row * D_ + e2] = f2bf(x2 * c + s * x1);
  }
}

// ---------------- V transpose per head: v[b][t][h*128+d] -> vt[bh][d][t] ----------------
__global__ void k_tv(const ushort_t* __restrict__ v, ushort_t* __restrict__ vt) {
  __shared__ ushort_t tile[32][33];
  int bh = blockIdx.z, b = bh >> 4, h = bh & 15;
  int tx = threadIdx.x, ty = threadIdx.y;
  int d = blockIdx.x * 32 + tx;
  int t0 = blockIdx.y * 32;
#pragma unroll
  for (int k = 0; k < 4; ++k)
    tile[ty + k * 8][tx] = v[(size_t)(b * T_ + t0 + ty + k * 8) * D_ + h * HD_ + d];
  __syncthreads();
  int ot = t0 + tx;
  int od0 = blockIdx.x * 32;
#pragma unroll
  for (int k = 0; k < 4; ++k)
    vt[((size_t)bh * HD_ + od0 + ty + k * 8) * T_ + ot] = tile[tx][ty + k * 8];
}

// ---------------- flash v4: S^T=K*Q^T (per-lane lsum), delayed PV (one barrier/iter),
// K and V double-buffered, P via swizzled LDS roundtrip synced by the iter barrier ----------------
__global__ __launch_bounds__(256) void k_flash(
    const ushort_t* __restrict__ Q, const ushort_t* __restrict__ K,
    const ushort_t* __restrict__ Vt, ushort_t* __restrict__ O) {
  __shared__ __align__(16) short Ks[2][64 * 128];   // [buf][key][d]
  __shared__ __align__(16) short Vs[2][128 * 64];   // [buf][d][key]
  __shared__ __align__(16) short Ps[4][32 * 64];    // per-wave P [q][key], 16B-chunk XOR swizzle

  const int tid = threadIdx.x;
  const int wid = tid >> 6, lane = tid & 63;
  const int l15 = lane & 15, kq = lane >> 4;
  const int l7 = l15 & 7;
  const int bh = blockIdx.y, b = bh >> 4, h = bh & 15;
  const int q0 = blockIdx.x * 128;

  const ushort_t* kp[4];
  const ushort_t* vp[4];
#pragma unroll
  for (int rr = 0; rr < 4; ++rr) {
    int c = rr * 256 + tid;
    int krow = c >> 4, kc = (c & 15) ^ (krow & 15);
    kp[rr] = K + (size_t)(b * T_ + krow) * D_ + h * HD_ + kc * 8;
    int drow = c >> 3, vc = (c & 7) ^ (drow & 7);
    vp[rr] = Vt + ((size_t)bh * HD_ + drow) * T_ + vc * 8;
  }

  // Q B-operand frags (B[n=q][k=d]: q=lane&15, d=quad*8+j — same shape as A), scale pre-folded
  bf16x8 qa0[4], qa1[4];
  {
    const ushort_t* qp0 = Q + (size_t)(b * T_ + q0 + wid * 32 + l15) * D_ + h * HD_ + kq * 8;
    const ushort_t* qp1 = qp0 + 16 * D_;
#pragma unroll
    for (int kk = 0; kk < 4; ++kk) {
      qa0[kk] = *(const bf16x8*)(qp0 + kk * 32);
      qa1[kk] = *(const bf16x8*)(qp1 + kk * 32);
    }
  }

  f32x4 o0[8], o1[8];
#pragma unroll
  for (int dt = 0; dt < 8; ++dt) {
    o0[dt] = (f32x4){0.f, 0.f, 0.f, 0.f};
    o1[dt] = (f32x4){0.f, 0.f, 0.f, 0.f};
  }
  float l0 = 0.f, l1 = 0.f;

  char* PsW = (char*)&Ps[wid][0];
  const int psr = (l15 * 128);            // row base for half0 (q = l15)

  // prologue: stage K(0) into buf 0
#pragma unroll
  for (int rr = 0; rr < 4; ++rr)
    async16(kp[rr], &Ks[0][(rr * 256 + wid * 64) * 8]);

  for (int kt = 0; kt < 32; ++kt) {
    const int kbuf = kt & 1;
    __syncthreads();   // drains K(kt) [+ V(kt-1)] staging; syncs Ps(kt-1) writes
    if (kt + 1 < 32) {
#pragma unroll
      for (int rr = 0; rr < 4; ++rr)
        async16(kp[rr] + (size_t)(kt + 1) * 64 * D_, &Ks[kbuf ^ 1][(rr * 256 + wid * 64) * 8]);
    }
#pragma unroll
    for (int rr = 0; rr < 4; ++rr)
      async16(vp[rr] + (size_t)kt * 64, &Vs[kbuf][(rr * 256 + wid * 64) * 8]);

    // P(kt-1) A-frags from Ps (written last iter; barrier synced)
    bf16x8 pa0[2], pa1[2];
    if (kt > 0) {
#pragma unroll
      for (int kk2 = 0; kk2 < 2; ++kk2) {
        int cs16 = ((kk2 * 4 + kq) ^ l7) * 16;
        pa0[kk2] = *(const bf16x8*)(PsW + psr + cs16);
        pa1[kk2] = *(const bf16x8*)(PsW + 2048 + psr + cs16);
      }
    }

    // S^T(kt) = K*Q^T: D[m=key][n=q] -> per lane: q=l15, key=j*16+kq*4+r
    f32x4 st0[4], st1[4];
#pragma unroll
    for (int j = 0; j < 4; ++j) { st0[j] = (f32x4){0.f,0.f,0.f,0.f}; st1[j] = (f32x4){0.f,0.f,0.f,0.f}; }
#pragma unroll
    for (int j = 0; j < 4; ++j) {
#pragma unroll
      for (int kk = 0; kk < 4; ++kk) {
        int row = j * 16 + l15;
        bf16x8 kf = *(const bf16x8*)&Ks[kbuf][row * 128 + ((kk * 4 + kq) ^ l15) * 8];
        st0[j] = __builtin_amdgcn_mfma_f32_16x16x32_bf16(kf, qa0[kk], st0[j], 0, 0, 0);
        st1[j] = __builtin_amdgcn_mfma_f32_16x16x32_bf16(kf, qa1[kk], st1[j], 0, 0, 0);
      }
    }

    // PV(kt-1): O[q][d] = P*V; A=pa (m=q), B=vf (n=d)
    if (kt > 0) {
#pragma unroll
      for (int kk2 = 0; kk2 < 2; ++kk2) {
#pragma unroll
        for (int dt = 0; dt < 8; ++dt) {
          bf16x8 vf = *(const bf16x8*)&Vs[kbuf ^ 1][(dt * 16 + l15) * 64 + ((kk2 * 4 + kq) ^ l7) * 8];
          o0[dt] = __builtin_amdgcn_mfma_f32_16x16x32_bf16(pa0[kk2], vf, o0[dt], 0, 0, 0);
          o1[dt] = __builtin_amdgcn_mfma_f32_16x16x32_bf16(pa1[kk2], vf, o1[dt], 0, 0, 0);
        }
      }
    }

    // softmax(kt): fixed-max exp2, per-lane lsum (q fixed = l15), pack+store P
#pragma unroll
    for (int j = 0; j < 4; ++j) {
      int cw16 = (((j * 2 + (kq >> 1)) ^ l7) * 16) + (kq & 1) * 8;
      {
        float p0 = __builtin_amdgcn_exp2f(st0[j][0]);
        float p1 = __builtin_amdgcn_exp2f(st0[j][1]);
        float p2 = __builtin_amdgcn_exp2f(st0[j][2]);
        float p3 = __builtin_amdgcn_exp2f(st0[j][3]);
        l0 += (p0 + p1) + (p2 + p3);
        uint32_t d0 = ((__float_as_uint(p0) + 0x8000u) >> 16) | ((__float_as_uint(p1) + 0x8000u) & 0xFFFF0000u);
        uint32_t d1 = ((__float_as_uint(p2) + 0x8000u) >> 16) | ((__float_as_uint(p3) + 0x8000u) & 0xFFFF0000u);
        *(uint2*)(PsW + psr + cw16) = make_uint2(d0, d1);
      }
      {
        float p0 = __builtin_amdgcn_exp2f(st1[j][0]);
        float p1 = __builtin_amdgcn_exp2f(st1[j][1]);
        float p2 = __builtin_amdgcn_exp2f(st1[j][2]);
        float p3 = __builtin_amdgcn_exp2f(st1[j][3]);
        l1 += (p0 + p1) + (p2 + p3);
        uint32_t d0 = ((__float_as_uint(p0) + 0x8000u) >> 16) | ((__float_as_uint(p1) + 0x8000u) & 0xFFFF0000u);
        uint32_t d1 = ((__float_as_uint(p2) + 0x8000u) >> 16) | ((__float_as_uint(p3) + 0x8000u) & 0xFFFF0000u);
        *(uint2*)(PsW + 2048 + psr + cw16) = make_uint2(d0, d1);
      }
    }
  }

  // epilogue: PV(31); V(31) staged during iter 31 -> barrier drains it
  __syncthreads();
  {
    bf16x8 pa0[2], pa1[2];
#pragma unroll
    for (int kk2 = 0; kk2 < 2; ++kk2) {
      int cs16 = ((kk2 * 4 + kq) ^ l7) * 16;
      pa0[kk2] = *(const bf16x8*)(PsW + psr + cs16);
      pa1[kk2] = *(const bf16x8*)(PsW + 2048 + psr + cs16);
    }
#pragma unroll
    for (int kk2 = 0; kk2 < 2; ++kk2) {
#pragma unroll
      for (int dt = 0; dt < 8; ++dt) {
        bf16x8 vf = *(const bf16x8*)&Vs[1][(dt * 16 + l15) * 64 + ((kk2 * 4 + kq) ^ l7) * 8];
        o0[dt] = __builtin_amdgcn_mfma_f32_16x16x32_bf16(pa0[kk2], vf, o0[dt], 0, 0, 0);
        o1[dt] = __builtin_amdgcn_mfma_f32_16x16x32_bf16(pa1[kk2], vf, o1[dt], 0, 0, 0);
      }
    }
  }

  // lsum: reduce across quads (q = l15 in every quad), then fetch per-output-row value
  l0 += __shfl_xor(l0, 16, 64); l0 += __shfl_xor(l0, 32, 64);
  l1 += __shfl_xor(l1, 16, 64); l1 += __shfl_xor(l1, 32, 64);
#pragma unroll
  for (int r = 0; r < 4; ++r) {
    float i0 = 1.f / __shfl(l0, kq * 4 + r, 64);
    float i1 = 1.f / __shfl(l1, kq * 4 + r, 64);
#pragma unroll
    for (int dt = 0; dt < 8; ++dt) {
      size_t idx = (size_t)(b * T_ + q0 + wid * 32 + kq * 4 + r) * D_ + h * HD_ + dt * 16 + l15;
      O[idx] = f2bf(o0[dt][r] * i0);
      O[idx + (size_t)16 * D_] = f2bf(o1[dt][r] * i1);
    }
  }
}

// ---------------- launch ----------------
extern "C" void kernel_launch(void* const* d_in, const int* in_sizes, int n_in,
                              void* d_out, int out_size, void* d_ws, size_t ws_size,
                              hipStream_t stream) {
  const float* x  = (const float*)d_in[0];
  const float* cs = (const float*)d_in[1];
  const float* sn = (const float*)d_in[2];
  const float* wq = (const float*)d_in[3];
  const float* bq = (const float*)d_in[4];
  const float* wk = (const float*)d_in[5];
  const float* bk = (const float*)d_in[6];
  const float* wv = (const float*)d_in[7];
  const float* bv = (const float*)d_in[8];
  const float* gq = (const float*)d_in[9];
  const float* gk = (const float*)d_in[10];
  const float* wo = (const float*)d_in[11];
  const float* bo = (const float*)d_in[12];
  const float* wg = (const float*)d_in[13];
  const float* bg = (const float*)d_in[14];

  char* ws = (char*)d_ws;
  const size_t SZ_BTD_BF = (size_t)BT_ * D_ * 2;   // 16 MB
  const size_t SZ_DD_BF  = (size_t)D_ * D_ * 2;    //  8 MB
  const size_t SZ_BTD_F  = (size_t)BT_ * D_ * 4;   // 32 MB

  size_t off = 0;
  ushort_t* xb  = (ushort_t*)(ws + off); off += SZ_BTD_BF;        // aliased as attn later
  ushort_t* wqT = (ushort_t*)(ws + off); off += SZ_DD_BF;
  ushort_t* wkT = (ushort_t*)(ws + off); off += SZ_DD_BF;
  ushort_t* wvT = (ushort_t*)(ws + off); off += SZ_DD_BF;
  ushort_t* woT = (ushort_t*)(ws + off); off += SZ_DD_BF;
  ushort_t* wgT = (ushort_t*)(ws + off); off += SZ_DD_BF;
  float*    qf  = (float*)(ws + off);    off += SZ_BTD_F;         // aliased as outf later
  float*    kf  = (float*)(ws + off);    off += SZ_BTD_F;         // aliased as outb later
  ushort_t* vb  = (ushort_t*)(ws + off); off += SZ_BTD_BF;
  ushort_t* qb  = (ushort_t*)(ws + off); off += SZ_BTD_BF;
  ushort_t* kb  = (ushort_t*)(ws + off); off += SZ_BTD_BF;
  ushort_t* vt  = (ushort_t*)(ws + off); off += SZ_BTD_BF;        // ~193 MB total
  ushort_t* attn = xb;            // xb dead after QKV GEMMs
  float*    outf = qf;            // qf dead after norm_rope(q)
  ushort_t* outb = (ushort_t*)kf; // kf dead after norm_rope(k)

  const float cl2 = 0.08838834764831845f * 1.4426950408889634f;  // 1/sqrt(128)*log2e

  k_cast_x<<<8192, 256, 0, stream>>>(x, xb);
  k_twT<<<dim3(64, 64), dim3(32, 8), 0, stream>>>(wq, wqT);
  k_twT<<<dim3(64, 64), dim3(32, 8), 0, stream>>>(wk, wkT);
  k_twT<<<dim3(64, 64), dim3(32, 8), 0, stream>>>(wv, wvT);
  k_twT<<<dim3(64, 64), dim3(32, 8), 0, stream>>>(wo, woT);
  k_twT<<<dim3(64, 64), dim3(32, 8), 0, stream>>>(wg, wgT);

  k_gemm<0><<<dim3(16, 32), 256, 0, stream>>>(xb, wqT, bq, qf, nullptr, nullptr);
  k_gemm<0><<<dim3(16, 32), 256, 0, stream>>>(xb, wkT, bk, kf, nullptr, nullptr);
  k_gemm<1><<<dim3(16, 32), 256, 0, stream>>>(xb, wvT, bv, nullptr, vb, nullptr);

  k_normrope<<<4096, 256, 0, stream>>>(qf, gq, cs, sn, qb, cl2);
  k_normrope<<<4096, 256, 0, stream>>>(kf, gk, cs, sn, kb, 1.0f);
  k_tv<<<dim3(4, 64, 32), dim3(32, 8), 0, stream>>>(vb, vt);

  k_flash<<<dim3(16, 32), 256, 0, stream>>>(qb, kb, vt, attn);

  k_gemm<2><<<dim3(16, 32), 256, 0, stream>>>(attn, woT, bo, outf, outb, nullptr);
  k_gemm<3><<<dim3(16, 32), 256, 0, stream>>>(outb, wgT, bg, (float*)d_out, nullptr, outf);
}